// Round 1
// 1961.508 us; speedup vs baseline: 1.2233x; 1.2233x over previous
//
#include <hip/hip_runtime.h>
#include <math.h>

// FrameTransformer v5: conversion-hoisted bf16-plane MFMA GEMMs.
// All fp32->bf16(hi/lo) splits happen ONCE at the producer:
//   - weights: wcvt_k once per layer (per call)
//   - norm'd activations: statsnorm_k (stats + norm + cvt fused)
//   - sqrelu activations: dwmix_k<1> / mm_k<EPI=1> epilogue
//   - attn output: attn_k epilogue
// mm_k is then a pure bf16 hi/lo GEMM (3-term split) staged via
// global_load_lds(16B) with XOR-pre-swizzled per-lane source addresses
// (linear LDS dest, swizzled ds_read -> conflict-free b128), double-buffered
// LDS (2x32KB) with one __syncthreads per K-step so the next-tile DMA
// overlaps the current tile's ds_read+MFMA.

typedef short s16x8 __attribute__((ext_vector_type(8)));
typedef float f32x4 __attribute__((ext_vector_type(4)));
typedef unsigned short u16;
#define MFMA(a,b,c) __builtin_amdgcn_mfma_f32_16x16x32_bf16(a,b,c,0,0,0)

__device__ __forceinline__ float4 ld4(const float* p){ return *(const float4*)p; }
__device__ __forceinline__ void st4(float* p, float4 v){ *(float4*)p = v; }
__device__ __forceinline__ float4 f4fma2(float a, float4 x, float b, float4 y){
  float4 r; r.x=a*x.x+b*y.x; r.y=a*x.y+b*y.y; r.z=a*x.z+b*y.z; r.w=a*x.w+b*y.w; return r;
}
__device__ __forceinline__ float4 f4add(float4 a, float4 b){
  float4 r; r.x=a.x+b.x; r.y=a.y+b.y; r.z=a.z+b.z; r.w=a.w+b.w; return r;
}
__device__ __forceinline__ float4 f4sqrelu(float4 a){
  float4 r;
  r.x = a.x>0.f ? a.x*a.x : 0.f; r.y = a.y>0.f ? a.y*a.y : 0.f;
  r.z = a.z>0.f ? a.z*a.z : 0.f; r.w = a.w>0.f ? a.w*a.w : 0.f;
  return r;
}

// split 8 floats -> bf16 hi/lo planes (truncation; lo captures residual)
__device__ __forceinline__ void cvt8(float4 a, float4 b, s16x8* hi, s16x8* lo){
  union { s16x8 v; unsigned short u[8]; } H, L;
  float f[8] = {a.x,a.y,a.z,a.w,b.x,b.y,b.z,b.w};
  #pragma unroll
  for (int j=0;j<8;j++){
    unsigned u = __float_as_uint(f[j]);
    H.u[j] = (unsigned short)(u>>16);
    float hf = __uint_as_float(u & 0xffff0000u);
    float lf = f[j] - hf;
    L.u[j] = (unsigned short)(__float_as_uint(lf)>>16);
  }
  *hi = H.v; *lo = L.v;
}

__device__ __forceinline__ void cvt4(float4 a, ushort4* hi, ushort4* lo){
  unsigned short hh[4], ll[4];
  float f[4] = {a.x,a.y,a.z,a.w};
  #pragma unroll
  for (int j=0;j<4;j++){
    unsigned u = __float_as_uint(f[j]);
    hh[j] = (unsigned short)(u>>16);
    float hf = __uint_as_float(u & 0xffff0000u);
    ll[j] = (unsigned short)(__float_as_uint(f[j]-hf)>>16);
  }
  ushort4 H, L;
  H.x=hh[0];H.y=hh[1];H.z=hh[2];H.w=hh[3];
  L.x=ll[0];L.y=ll[1];L.z=ll[2];L.w=ll[3];
  *hi=H; *lo=L;
}

// async global->LDS, 16B per lane, wave-uniform LDS base (per-lane global src)
__device__ __forceinline__ void gl16(const void* g, void* l){
  __builtin_amdgcn_global_load_lds((const __attribute__((address_space(1))) void*)g,
                                   (__attribute__((address_space(3))) void*)l, 16, 0, 0);
}

// ---------------- rope table: cos/sin[w][j], j=0..31 ----------------
__global__ __launch_bounds__(256) void rope_tab_k(float* __restrict__ cosT, float* __restrict__ sinT){
  int idx = blockIdx.x*256 + threadIdx.x;   // 512*32
  int w = idx >> 5, j = idx & 31;
  float th = (float)w * powf(10000.f, -(float)(2*j)/64.f);
  cosT[idx] = cosf(th);
  sinT[idx] = sinf(th);
}

// ---------------- weight conversion: fp32 -> bf16 hi/lo planes ----------------
// VAR=0: layer {q,k,v,o,f1,f2}; VAR=1: enc {e1,e2,ei}; VAR=2: dec {d1,d2,di}
template<int VAR>
__global__ __launch_bounds__(256) void wcvt_k(
    const float* __restrict__ s0, const float* __restrict__ s1, const float* __restrict__ s2,
    const float* __restrict__ s3, const float* __restrict__ s4, const float* __restrict__ s5,
    u16* __restrict__ H, u16* __restrict__ L)
{
  const int seg = blockIdx.y;
  const float* src; int n; size_t off;
  if (VAR == 0){
    if      (seg==0){ src=s0; n= 524288; off=0; }
    else if (seg==1){ src=s1; n= 524288; off= 524288; }
    else if (seg==2){ src=s2; n= 524288; off=1048576; }
    else if (seg==3){ src=s3; n= 524288; off=1572864; }
    else if (seg==4){ src=s4; n=2097152; off=2097152; }
    else            { src=s5; n=2097152; off=4194304; }
  } else if (VAR == 1){
    if      (seg==0){ src=s0; n=1048576; off=0; }
    else if (seg==1){ src=s1; n= 524288; off=1048576; }
    else            { src=s2; n=1048576; off=1572864; }
  } else {
    if      (seg==0){ src=s0; n=1048576; off=0; }
    else if (seg==1){ src=s1; n=2097152; off=1048576; }
    else            { src=s2; n=1048576; off=3145728; }
  }
  const int idx = blockIdx.x*256 + threadIdx.x;
  if (idx*8 >= n) return;
  float4 a = ld4(src + (size_t)idx*8);
  float4 b = ld4(src + (size_t)idx*8 + 4);
  s16x8 h,l; cvt8(a,b,&h,&l);
  *(s16x8*)&H[off + (size_t)idx*8] = h;
  *(s16x8*)&L[off + (size_t)idx*8] = l;
}

// ---------------- plain fp32 -> bf16 hi/lo planes (1M elems) ----------------
__global__ __launch_bounds__(256) void cvt_k(const float* __restrict__ X,
                                             u16* __restrict__ H, u16* __restrict__ L){
  const int idx = blockIdx.x*256 + threadIdx.x;
  float4 a = ld4(X + (size_t)idx*8);
  float4 b = ld4(X + (size_t)idx*8 + 4);
  s16x8 h,l; cvt8(a,b,&h,&l);
  *(s16x8*)&H[(size_t)idx*8] = h;
  *(s16x8*)&L[(size_t)idx*8] = l;
}

// ---------------- fused frame-norm stats + normalize + cvt: one wave per row ----------------
__global__ __launch_bounds__(256) void statsnorm_k(
    const float* __restrict__ E, const float* __restrict__ G, const float* __restrict__ Bt,
    u16* __restrict__ BH, u16* __restrict__ BL)
{
  int row = (blockIdx.x<<2) + (threadIdx.x>>6);
  int lane = threadIdx.x & 63;
  int c = (row >> 9) & 1;
  const float* p = E + (size_t)row*512 + (lane<<3);
  float4 a = ld4(p), b = ld4(p+4);
  float s = a.x+a.y+a.z+a.w + b.x+b.y+b.z+b.w;
  float q = a.x*a.x+a.y*a.y+a.z*a.z+a.w*a.w + b.x*b.x+b.y*b.y+b.z*b.z+b.w*b.w;
  #pragma unroll
  for (int off=32; off; off>>=1){ s += __shfl_xor(s,off); q += __shfl_xor(q,off); }
  float mu = s*(1.f/512.f);
  float rs = rsqrtf(q*(1.f/512.f) - mu*mu + 1e-5f);
  const float* gp = G  + c*512 + (lane<<3);
  const float* bp = Bt + c*512 + (lane<<3);
  float4 g0 = ld4(gp), g1 = ld4(gp+4), b0 = ld4(bp), b1 = ld4(bp+4);
  a.x = (a.x-mu)*rs*g0.x + b0.x; a.y = (a.y-mu)*rs*g0.y + b0.y;
  a.z = (a.z-mu)*rs*g0.z + b0.z; a.w = (a.w-mu)*rs*g0.w + b0.w;
  b.x = (b.x-mu)*rs*g1.x + b1.x; b.y = (b.y-mu)*rs*g1.y + b1.y;
  b.z = (b.z-mu)*rs*g1.z + b1.z; b.w = (b.w-mu)*rs*g1.w + b1.w;
  s16x8 h,l; cvt8(a,b,&h,&l);
  size_t o = (size_t)row*512 + (lane<<3);
  *(s16x8*)&BH[o] = h; *(s16x8*)&BL[o] = l;
}

// ---------------- MFMA GEMM on bf16 hi/lo planes ----------------
// 64x64 tile, BK=64, 4 waves (2x2 of 32x32), 3-term split.
// LDS double-buffered (2 x 32KB); staging via global_load_lds with
// XOR-swizzled source chunk (chunk ^= row&7) so ds_read_b128 is conflict-free.
template<int EPI, bool ACC, bool FUSE3>
__global__ __launch_bounds__(256) void mm_k(
    const u16* __restrict__ AH_, const u16* __restrict__ AL_,
    const u16* __restrict__ BH_, const u16* __restrict__ BL_,
    float* __restrict__ Y_, u16* __restrict__ YH_, u16* __restrict__ YL_,
    int M, int K)
{
  const int z = blockIdx.z;
  const int bc = FUSE3 ? (z & 3) : z;
  const int c = bc & 1;
  const size_t aoff = (size_t)c*M*K + (FUSE3 ? (size_t)(z>>2)*524288 : (size_t)0);
  const u16* AHp = AH_ + aoff;
  const u16* ALp = AL_ + aoff;
  const u16* BHp = BH_ + (size_t)bc*512*K;
  const u16* BLp = BL_ + (size_t)bc*512*K;

  const int n0 = blockIdx.x << 6, m0 = blockIdx.y << 6;
  const int t = threadIdx.x;
  const int lane = t & 63, wv = t >> 6;

  __shared__ __align__(16) unsigned char smem[65536];
  u16* sm = (u16*)smem;

  // staging geometry: per wave per plane-tile: 2 issues of 1KB (8 rows x 8 chunks)
  const int Rb  = wv*16 + (lane>>3);                 // j=0 row (j=1: +8)
  const int sc8 = ((lane & 7) ^ (Rb & 7)) << 3;      // swizzled source chunk (elems)
  const u16* gA0 = AHp + (size_t)(m0+Rb)*K + sc8;
  const u16* gA1 = ALp + (size_t)(m0+Rb)*K + sc8;
  const u16* gB0 = BHp + (size_t)(n0+Rb)*K + sc8;
  const u16* gB1 = BLp + (size_t)(n0+Rb)*K + sc8;
  const size_t r8 = (size_t)8*K;

  auto stage = [&](int half, int kt){
    u16* lb = sm + (half<<14) + (wv<<10);
    const int k64 = kt << 6;
    gl16(gA0 + k64,      lb);
    gl16(gA0 + r8 + k64, lb + 512);
    gl16(gA1 + k64,      lb + 4096);
    gl16(gA1 + r8 + k64, lb + 4608);
    gl16(gB0 + k64,      lb + 8192);
    gl16(gB0 + r8 + k64, lb + 8704);
    gl16(gB1 + k64,      lb + 12288);
    gl16(gB1 + r8 + k64, lb + 12800);
  };

  const int fr = lane & 15, fq = lane >> 4;
  const int mq = (wv >> 1) << 5, nq = (wv & 1) << 5;
  const int ra0 = (mq + fr)<<6, ra1 = (mq + 16 + fr)<<6;
  const int rb0 = (nq + fr)<<6, rb1 = (nq + 16 + fr)<<6;
  const int frx = fr & 7;

  f32x4 acc00 = {0,0,0,0}, acc01 = {0,0,0,0}, acc10 = {0,0,0,0}, acc11 = {0,0,0,0};
  const int NT = K >> 6;

  stage(0, 0);
  __syncthreads();
  for (int kt = 0; kt < NT; kt++){
    if (kt + 1 < NT) stage((kt+1)&1, kt+1);
    const u16* cb = sm + ((kt&1)<<14);
    #pragma unroll
    for (int ks = 0; ks < 64; ks += 32){
      const int cs = ((((ks>>3) + fq) ^ frx) << 3);
      s16x8 aH0 = *(const s16x8*)&cb[ra0 + cs];
      s16x8 aH1 = *(const s16x8*)&cb[ra1 + cs];
      s16x8 aL0 = *(const s16x8*)&cb[4096 + ra0 + cs];
      s16x8 aL1 = *(const s16x8*)&cb[4096 + ra1 + cs];
      s16x8 bH0 = *(const s16x8*)&cb[8192 + rb0 + cs];
      s16x8 bH1 = *(const s16x8*)&cb[8192 + rb1 + cs];
      s16x8 bL0 = *(const s16x8*)&cb[12288 + rb0 + cs];
      s16x8 bL1 = *(const s16x8*)&cb[12288 + rb1 + cs];
      acc00 = MFMA(aH0,bH0,acc00); acc00 = MFMA(aH0,bL0,acc00); acc00 = MFMA(aL0,bH0,acc00);
      acc01 = MFMA(aH0,bH1,acc01); acc01 = MFMA(aH0,bL1,acc01); acc01 = MFMA(aL0,bH1,acc01);
      acc10 = MFMA(aH1,bH0,acc10); acc10 = MFMA(aH1,bL0,acc10); acc10 = MFMA(aL1,bH0,acc10);
      acc11 = MFMA(aH1,bH1,acc11); acc11 = MFMA(aH1,bL1,acc11); acc11 = MFMA(aL1,bH1,acc11);
    }
    __syncthreads();
  }

  float* Yt = (float*)smem;    // [64][72]
  #pragma unroll
  for (int i=0;i<4;i++){
    Yt[(nq      + fr)*72 + mq      + fq*4 + i] = acc00[i];
    Yt[(nq + 16 + fr)*72 + mq      + fq*4 + i] = acc01[i];
    Yt[(nq      + fr)*72 + mq + 16 + fq*4 + i] = acc10[i];
    Yt[(nq + 16 + fr)*72 + mq + 16 + fq*4 + i] = acc11[i];
  }
  __syncthreads();
  const int sr = t >> 2, scB = (t & 3) << 4;
  if (EPI == 1){
    float4 r0 = f4sqrelu(*(float4*)&Yt[sr*72 + scB]);
    float4 r1 = f4sqrelu(*(float4*)&Yt[sr*72 + scB + 4]);
    float4 r2 = f4sqrelu(*(float4*)&Yt[sr*72 + scB + 8]);
    float4 r3 = f4sqrelu(*(float4*)&Yt[sr*72 + scB + 12]);
    u16* YH = YH_ + (size_t)bc*512*M;
    u16* YL = YL_ + (size_t)bc*512*M;
    size_t base = (size_t)(n0 + sr)*M + m0 + scB;
    s16x8 h,l;
    cvt8(r0,r1,&h,&l); *(s16x8*)&YH[base]   = h; *(s16x8*)&YL[base]   = l;
    cvt8(r2,r3,&h,&l); *(s16x8*)&YH[base+8] = h; *(s16x8*)&YL[base+8] = l;
  } else {
    float* Y = Y_ + (FUSE3 ? (size_t)(z>>2)*1048576 : (size_t)0) + (size_t)bc*512*M;
    #pragma unroll
    for (int i=0;i<4;i++){
      float4 r = *(float4*)&Yt[sr*72 + scB + i*4];
      float* dst = &Y[(size_t)(n0 + sr)*M + m0 + scB + i*4];
      if (ACC) r = f4add(r, ld4(dst));
      st4(dst, r);
    }
  }
}

// ---------------- channel mix (dw); MODE=1 writes sqrelu'd bf16 hi/lo planes ----------------
template<int MODE>
__global__ __launch_bounds__(256) void dwmix_k(
    const float* __restrict__ T, const float* __restrict__ dwp,
    const float* __restrict__ Z, float* __restrict__ O,
    u16* __restrict__ OH, u16* __restrict__ OL, int F)
{
  int idx = blockIdx.x*256 + threadIdx.x;
  int perb = F << 7;
  int b = idx / perb; int rem = idx - b*perb;
  size_t i0 = ((size_t)(b*2) * F)*512 + (size_t)rem*4;
  size_t i1 = i0 + (size_t)F*512;
  float4 t0 = ld4(T + i0), t1 = ld4(T + i1);
  float d00 = dwp[0], d01 = dwp[1], d10 = dwp[2], d11 = dwp[3];
  float4 o0 = f4fma2(d00, t0, d01, t1);
  float4 o1 = f4fma2(d10, t0, d11, t1);
  if (MODE == 1){
    o0 = f4sqrelu(o0); o1 = f4sqrelu(o1);
    ushort4 h,l;
    cvt4(o0,&h,&l); *(ushort4*)&OH[i0] = h; *(ushort4*)&OL[i0] = l;
    cvt4(o1,&h,&l); *(ushort4*)&OH[i1] = h; *(ushort4*)&OL[i1] = l;
  } else if (MODE == 2){
    o0 = f4add(o0, ld4(Z + i0)); o1 = f4add(o1, ld4(Z + i1));
    st4(O + i0, o0); st4(O + i1, o1);
  } else {
    st4(O + i0, o0); st4(O + i1, o1);
  }
}

// ---------------- fused qkv post: dw-mix (+rope for q,k), wf layout ----------------
__global__ __launch_bounds__(256) void qkv_post_k(
    const float* __restrict__ QY, const float* __restrict__ qdw,
    const float* __restrict__ kdw, const float* __restrict__ vdw,
    float* __restrict__ qB, float* __restrict__ kB, float* __restrict__ vB,
    const float* __restrict__ cosT, const float* __restrict__ sinT)
{
  int p = blockIdx.y;
  const float* T = QY + (size_t)p*1048576;
  const float* dwp = (p==0) ? qdw : ((p==1) ? kdw : vdw);
  float* O = (p==0) ? qB : ((p==1) ? kB : vB);
  int idx = blockIdx.x*256 + threadIdx.x;
  int b = idx >> 16; int rem = idx & 65535;
  int w = rem >> 7; int f = (rem & 127) << 2;
  size_t i0 = ((size_t)(b*2)*512 + w)*512 + f;
  size_t i1 = i0 + 262144;
  float4 t0 = ld4(T+i0), t1 = ld4(T+i1);
  float d00 = dwp[0], d01 = dwp[1], d10 = dwp[2], d11 = dwp[3];
  float4 o0 = f4fma2(d00, t0, d01, t1);
  float4 o1 = f4fma2(d10, t0, d11, t1);
  if (p < 2){
    int j = (f & 63) >> 1;
    float c0 = cosT[w*32 + j], c1 = cosT[w*32 + j + 1];
    float s0 = sinT[w*32 + j], s1 = sinT[w*32 + j + 1];
    float4 r0, r1;
    r0.x = o0.x*c0 - o0.y*s0;  r0.y = o0.y*c0 + o0.x*s0;
    r0.z = o0.z*c1 - o0.w*s1;  r0.w = o0.w*c1 + o0.z*s1;
    r1.x = o1.x*c0 - o1.y*s0;  r1.y = o1.y*c0 + o1.x*s0;
    r1.z = o1.z*c1 - o1.w*s1;  r1.w = o1.w*c1 + o1.z*s1;
    o0 = r0; o1 = r1;
  }
  st4(O + i0, o0);
  st4(O + i1, o1);
}

// ---------------- transpose x: [bc][1024 f][512 w] -> bf16 hi/lo [bc][512 w][1024 f] ----------------
__global__ __launch_bounds__(256) void transpose_x_k(const float* __restrict__ X,
                                                     u16* __restrict__ XH, u16* __restrict__ XL){
  __shared__ float T[64][68];
  int w0 = blockIdx.x << 6, f0 = blockIdx.y << 6, bc = blockIdx.z;
  int r = threadIdx.x >> 2, c4 = (threadIdx.x & 3) << 4;
  const float* src = X + ((size_t)bc*1024 + f0 + r)*512 + w0 + c4;
  #pragma unroll
  for (int i=0;i<4;i++) st4(&T[r][c4 + i*4], ld4(src + i*4));
  __syncthreads();
  size_t base = ((size_t)bc*512 + w0 + r)*1024 + f0 + c4;
  #pragma unroll
  for (int i=0;i<2;i++){
    float4 v0, v1;
    v0.x = T[c4+i*8+0][r]; v0.y = T[c4+i*8+1][r]; v0.z = T[c4+i*8+2][r]; v0.w = T[c4+i*8+3][r];
    v1.x = T[c4+i*8+4][r]; v1.y = T[c4+i*8+5][r]; v1.z = T[c4+i*8+6][r]; v1.w = T[c4+i*8+7][r];
    s16x8 h,l; cvt8(v0,v1,&h,&l);
    *(s16x8*)&XH[base + i*8] = h;
    *(s16x8*)&XL[base + i*8] = l;
  }
}

// ---------------- final: dw-mix + add Z, transpose wf -> (b,c,1024,512) ----------------
__global__ __launch_bounds__(256) void out_t_k(const float* __restrict__ T_, const float* __restrict__ dwp,
                                               const float* __restrict__ Z, float* __restrict__ O){
  __shared__ float T0[64][68], T1[64][68];
  int w0 = blockIdx.x << 6, f0 = blockIdx.y << 6, b = blockIdx.z;
  int r = threadIdx.x >> 2, c4 = (threadIdx.x & 3) << 4;
  size_t base0 = ((size_t)(b*2)*512 + w0 + r)*1024 + f0 + c4;
  size_t base1 = base0 + 524288;
  float d00 = dwp[0], d01 = dwp[1], d10 = dwp[2], d11 = dwp[3];
  #pragma unroll
  for (int i=0;i<4;i++){
    float4 t0 = ld4(T_+base0+i*4), t1 = ld4(T_+base1+i*4);
    float4 z0 = ld4(Z+base0+i*4),  z1 = ld4(Z+base1+i*4);
    st4(&T0[r][c4+i*4], f4add(f4fma2(d00,t0,d01,t1), z0));
    st4(&T1[r][c4+i*4], f4add(f4fma2(d10,t0,d11,t1), z1));
  }
  __syncthreads();
  size_t ob0 = ((size_t)(b*2)*1024 + f0 + r)*512 + w0 + c4;
  size_t ob1 = ob0 + 524288;
  #pragma unroll
  for (int i=0;i<4;i++){
    float4 v0, v1;
    v0.x=T0[c4+i*4+0][r]; v0.y=T0[c4+i*4+1][r]; v0.z=T0[c4+i*4+2][r]; v0.w=T0[c4+i*4+3][r];
    v1.x=T1[c4+i*4+0][r]; v1.y=T1[c4+i*4+1][r]; v1.z=T1[c4+i*4+2][r]; v1.w=T1[c4+i*4+3][r];
    st4(O+ob0+i*4, v0);
    st4(O+ob1+i*4, v1);
  }
}

// ---------------- MFMA fused attention, wf layout (output -> bf16 hi/lo planes) ----------------
__global__ __launch_bounds__(256) void attn_k(
    const float* __restrict__ Q, const float* __restrict__ K,
    const float* __restrict__ V, u16* __restrict__ aoH, u16* __restrict__ aoL)
{
  const int q0 = blockIdx.x << 6;
  const int hc = blockIdx.y << 6;
  const int bc = blockIdx.z;
  const size_t cb = (size_t)bc*262144;
  const float* Qp = Q + cb;
  const float* Kp = K + cb;
  const float* Vp = V + cb;

  __shared__ __align__(16) unsigned short QH[64*72];
  __shared__ __align__(16) unsigned short QL[64*72];
  __shared__ __align__(16) unsigned short TH[64*72];
  __shared__ __align__(16) unsigned short TL[64*72];
  __shared__ float St[64*68];
  __shared__ float mL[64], lL[64], aLs[64];

  const int t = threadIdx.x, lane = t & 63, wv = t >> 6;
  const int fr = lane & 15, fq = lane >> 4;
  const int mq = wv << 4;

  {
    int r = t >> 2, c16 = (t & 3) << 4;
    const float* src = Qp + (size_t)(q0 + r)*512 + hc + c16;
    float4 v0 = ld4(src), v1 = ld4(src+4), v2 = ld4(src+8), v3 = ld4(src+12);
    s16x8 h,l;
    cvt8(v0,v1,&h,&l); *(s16x8*)&QH[r*72+c16]   = h; *(s16x8*)&QL[r*72+c16]   = l;
    cvt8(v2,v3,&h,&l); *(s16x8*)&QH[r*72+c16+8] = h; *(s16x8*)&QL[r*72+c16+8] = l;
  }
  if (t < 64){ mL[t] = -1e30f; lL[t] = 0.f; }

  f32x4 oA[4] = {{0,0,0,0},{0,0,0,0},{0,0,0,0},{0,0,0,0}};
  const float sc = 0.044194173824159216f;

  for (int k0 = 0; k0 < 512; k0 += 64){
    __syncthreads();
    {
      int r = t >> 2, c16 = (t & 3) << 4;
      const float* src = Kp + (size_t)(k0 + r)*512 + hc + c16;
      float4 v0 = ld4(src), v1 = ld4(src+4), v2 = ld4(src+8), v3 = ld4(src+12);
      s16x8 h,l;
      cvt8(v0,v1,&h,&l); *(s16x8*)&TH[r*72+c16]   = h; *(s16x8*)&TL[r*72+c16]   = l;
      cvt8(v2,v3,&h,&l); *(s16x8*)&TH[r*72+c16+8] = h; *(s16x8*)&TL[r*72+c16+8] = l;
    }
    __syncthreads();
    {
      f32x4 sA[4] = {{0,0,0,0},{0,0,0,0},{0,0,0,0},{0,0,0,0}};
      #pragma unroll
      for (int ks = 0; ks < 64; ks += 32){
        int ao = (mq + fr)*72 + ks + fq*8;
        s16x8 aH = *(const s16x8*)&QH[ao];
        s16x8 aLo = *(const s16x8*)&QL[ao];
        #pragma unroll
        for (int nt = 0; nt < 4; nt++){
          int bo = ((nt<<4) + fr)*72 + ks + fq*8;
          s16x8 bH = *(const s16x8*)&TH[bo];
          s16x8 bLo = *(const s16x8*)&TL[bo];
          sA[nt] = MFMA(aH,bH,sA[nt]);
          sA[nt] = MFMA(aLo,bH,sA[nt]);
          sA[nt] = MFMA(aH,bLo,sA[nt]);
        }
      }
      #pragma unroll
      for (int nt = 0; nt < 4; nt++)
        #pragma unroll
        for (int i = 0; i < 4; i++)
          St[(mq + fq*4 + i)*68 + (nt<<4) + fr] = sA[nt][i]*sc;
    }
    __syncthreads();
    {
      int r = t >> 2, sub = t & 3;
      float* row = &St[r*68 + (sub << 4)];
      float4 x0 = ((float4*)row)[0], x1 = ((float4*)row)[1];
      float4 x2 = ((float4*)row)[2], x3 = ((float4*)row)[3];
      float mx = fmaxf(fmaxf(fmaxf(x0.x,x0.y),fmaxf(x0.z,x0.w)),
                       fmaxf(fmaxf(x1.x,x1.y),fmaxf(x1.z,x1.w)));
      mx = fmaxf(mx, fmaxf(fmaxf(fmaxf(x2.x,x2.y),fmaxf(x2.z,x2.w)),
                           fmaxf(fmaxf(x3.x,x3.y),fmaxf(x3.z,x3.w))));
      mx = fmaxf(mx, __shfl_xor(mx, 1));
      mx = fmaxf(mx, __shfl_xor(mx, 2));
      float mo = mL[r];
      float mn = fmaxf(mo, mx);
      float al = __expf(mo - mn);
      x0.x=__expf(x0.x-mn); x0.y=__expf(x0.y-mn); x0.z=__expf(x0.z-mn); x0.w=__expf(x0.w-mn);
      x1.x=__expf(x1.x-mn); x1.y=__expf(x1.y-mn); x1.z=__expf(x1.z-mn); x1.w=__expf(x1.w-mn);
      x2.x=__expf(x2.x-mn); x2.y=__expf(x2.y-mn); x2.z=__expf(x2.z-mn); x2.w=__expf(x2.w-mn);
      x3.x=__expf(x3.x-mn); x3.y=__expf(x3.y-mn); x3.z=__expf(x3.z-mn); x3.w=__expf(x3.w-mn);
      float sm = (x0.x+x0.y+x0.z+x0.w) + (x1.x+x1.y+x1.z+x1.w)
               + (x2.x+x2.y+x2.z+x2.w) + (x3.x+x3.y+x3.z+x3.w);
      sm += __shfl_xor(sm, 1);
      sm += __shfl_xor(sm, 2);
      ((float4*)row)[0]=x0; ((float4*)row)[1]=x1; ((float4*)row)[2]=x2; ((float4*)row)[3]=x3;
      if (sub == 0){ mL[r] = mn; lL[r] = lL[r]*al + sm; aLs[r] = al; }
    }
    {
      int c16 = wv << 4;
      const float* src = Vp + (size_t)(k0 + lane)*512 + hc + c16;
      #pragma unroll
      for (int jj = 0; jj < 16; jj += 4){
        float4 v = ld4(src + jj);
        float f[4] = {v.x, v.y, v.z, v.w};
        #pragma unroll
        for (int e = 0; e < 4; e++){
          unsigned u = __float_as_uint(f[e]);
          TH[(c16+jj+e)*72 + lane] = (unsigned short)(u>>16);
          float hf = __uint_as_float(u & 0xffff0000u);
          TL[(c16+jj+e)*72 + lane] = (unsigned short)(__float_as_uint(f[e]-hf)>>16);
        }
      }
    }
    __syncthreads();
    {
      float a0 = aLs[mq + fq*4 + 0], a1 = aLs[mq + fq*4 + 1];
      float a2 = aLs[mq + fq*4 + 2], a3 = aLs[mq + fq*4 + 3];
      #pragma unroll
      for (int nt = 0; nt < 4; nt++){
        oA[nt][0] *= a0; oA[nt][1] *= a1; oA[nt][2] *= a2; oA[nt][3] *= a3;
      }
      #pragma unroll
      for (int ks = 0; ks < 64; ks += 32){
        const float* pr = &St[(mq + fr)*68 + ks + fq*8];
        float4 p0 = ld4(pr), p1 = ld4(pr+4);
        s16x8 pH, pL;
        cvt8(p0, p1, &pH, &pL);
        #pragma unroll
        for (int nt = 0; nt < 4; nt++){
          int bo = ((nt<<4) + fr)*72 + ks + fq*8;
          s16x8 bH = *(const s16x8*)&TH[bo];
          s16x8 bLo = *(const s16x8*)&TL[bo];
          oA[nt] = MFMA(pH,bH,oA[nt]);
          oA[nt] = MFMA(pL,bH,oA[nt]);
          oA[nt] = MFMA(pH,bLo,oA[nt]);
        }
      }
    }
  }
  {
    float i0 = 1.f / lL[mq + fq*4 + 0], i1 = 1.f / lL[mq + fq*4 + 1];
    float i2 = 1.f / lL[mq + fq*4 + 2], i3 = 1.f / lL[mq + fq*4 + 3];
    #pragma unroll
    for (int nt = 0; nt < 4; nt++){
      St[(mq + fq*4 + 0)*68 + (nt<<4) + fr] = oA[nt][0]*i0;
      St[(mq + fq*4 + 1)*68 + (nt<<4) + fr] = oA[nt][1]*i1;
      St[(mq + fq*4 + 2)*68 + (nt<<4) + fr] = oA[nt][2]*i2;
      St[(mq + fq*4 + 3)*68 + (nt<<4) + fr] = oA[nt][3]*i3;
    }
  }
  __syncthreads();
  {
    int r = t >> 2, c16 = (t & 3) << 4;
    size_t base = cb + (size_t)(q0 + r)*512 + hc + c16;
    float4 v0 = *(float4*)&St[r*68 + c16];
    float4 v1 = *(float4*)&St[r*68 + c16 + 4];
    float4 v2 = *(float4*)&St[r*68 + c16 + 8];
    float4 v3 = *(float4*)&St[r*68 + c16 + 12];
    s16x8 h,l;
    cvt8(v0,v1,&h,&l); *(s16x8*)&aoH[base]   = h; *(s16x8*)&aoL[base]   = l;
    cvt8(v2,v3,&h,&l); *(s16x8*)&aoH[base+8] = h; *(s16x8*)&aoL[base+8] = l;
  }
}

extern "C" void kernel_launch(void* const* d_in, const int* in_sizes, int n_in,
                              void* d_out, int out_size, void* d_ws, size_t ws_size,
                              hipStream_t stream) {
  (void)in_sizes; (void)n_in; (void)out_size; (void)ws_size;
  const float* x     = (const float*)d_in[0];
  const float* e1_pw = (const float*)d_in[1];
  const float* e1_dw = (const float*)d_in[2];
  const float* e2_pw = (const float*)d_in[3];
  const float* e2_dw = (const float*)d_in[4];
  const float* ei_pw = (const float*)d_in[5];
  const float* ei_dw = (const float*)d_in[6];
  const float* n1_w  = (const float*)d_in[7];
  const float* n1_b  = (const float*)d_in[8];
  const float* q_pw  = (const float*)d_in[9];
  const float* q_dw  = (const float*)d_in[10];
  const float* k_pw  = (const float*)d_in[11];
  const float* k_dw  = (const float*)d_in[12];
  const float* v_pw  = (const float*)d_in[13];
  const float* v_dw  = (const float*)d_in[14];
  const float* o_pw  = (const float*)d_in[15];
  const float* n2_w  = (const float*)d_in[16];
  const float* n2_b  = (const float*)d_in[17];
  const float* f1_pw = (const float*)d_in[18];
  const float* f2_pw = (const float*)d_in[19];
  const float* d1_pw = (const float*)d_in[20];
  const float* d1_dw = (const float*)d_in[21];
  const float* d2_pw = (const float*)d_in[22];
  const float* d2_dw = (const float*)d_in[23];
  const float* di_pw = (const float*)d_in[24];
  const float* di_dw = (const float*)d_in[25];

  float* W    = (float*)d_ws;
  float* bufA = W;                        // 3,145,728 f
  float* eB   = W + 3145728;              // 1,048,576
  float* qB   = W + 4194304;              // 1,048,576
  float* kB   = W + 5242880;              // 1,048,576
  float* vB   = W + 6291456;              // 1,048,576
  float* Zbuf = W + 7340032;              // 2,097,152 (enc uses 1M, dec 2M)
  float* cosT = W + 9437184;              // 16,384
  float* sinT = W + 9453568;              // 16,384
  u16* P   = (u16*)(W + 9469952);         // bf16 plane pool
  u16* xTH = P;                           // 2,097,152
  u16* xTL = xTH + 2097152;
  u16* nBH = xTL + 2097152;               // 1,048,576
  u16* nBL = nBH + 1048576;
  u16* aoH = nBL + 1048576;               // 1,048,576
  u16* aoL = aoH + 1048576;
  u16* f2H = aoL + 1048576;               // 4,194,304
  u16* f2L = f2H + 4194304;
  u16* sqH = f2L + 4194304;               // 2,097,152
  u16* sqL = sqH + 2097152;
  u16* ePH = sqL + 2097152;               // 1,048,576
  u16* ePL = ePH + 1048576;
  u16* LWH = ePL + 1048576;               // 6,291,456 (per-layer weight planes)
  u16* LWL = LWH + 6291456;
  float* os = (float*)d_out;

  const dim3 blk(256);

  rope_tab_k<<<64, blk, 0, stream>>>(cosT, sinT);
  transpose_x_k<<<dim3(8,16,4), blk, 0, stream>>>(x, xTH, xTL);

  // ---- encoder frame_block ----
  wcvt_k<1><<<dim3(512,3), blk, 0, stream>>>(e1_pw, e2_pw, ei_pw, nullptr, nullptr, nullptr, LWH, LWL);
  mm_k<0,false,false><<<dim3(8,8,4), blk, 0, stream>>>(LWH, LWL, xTH, xTL, bufA, nullptr, nullptr, 512, 1024);
  dwmix_k<1><<<512, blk, 0, stream>>>(bufA, e1_dw, nullptr, nullptr, sqH, sqL, 512);
  mm_k<0,false,false><<<dim3(8,8,4), blk, 0, stream>>>(LWH+1048576, LWL+1048576, sqH, sqL, bufA, nullptr, nullptr, 512, 512);
  dwmix_k<0><<<512, blk, 0, stream>>>(bufA, e2_dw, nullptr, Zbuf, nullptr, nullptr, 512);
  mm_k<0,false,false><<<dim3(8,8,4), blk, 0, stream>>>(LWH+1572864, LWL+1572864, xTH, xTL, bufA, nullptr, nullptr, 512, 1024);
  dwmix_k<2><<<512, blk, 0, stream>>>(bufA, ei_dw, Zbuf, eB, nullptr, nullptr, 512);

  // ---- 12 layers ----
  for (int i = 0; i < 12; i++){
    const float* n1w = n1_w + i*1024; const float* n1b = n1_b + i*1024;
    const float* n2w = n2_w + i*1024; const float* n2b = n2_b + i*1024;
    size_t qo = (size_t)i*524288, fo = (size_t)i*2097152;

    wcvt_k<0><<<dim3(1024,6), blk, 0, stream>>>(q_pw+qo, k_pw+qo, v_pw+qo, o_pw+qo, f1_pw+fo, f2_pw+fo, LWH, LWL);
    statsnorm_k<<<512, blk, 0, stream>>>(eB, n1w, n1b, nBH, nBL);
    mm_k<0,false,true><<<dim3(8,8,12), blk, 0, stream>>>(LWH, LWL, nBH, nBL, bufA, nullptr, nullptr, 512, 512);
    qkv_post_k<<<dim3(512,3), blk, 0, stream>>>(bufA, q_dw+i*4, k_dw+i*4, v_dw+i*4, qB, kB, vB, cosT, sinT);
    attn_k<<<dim3(8,8,4), blk, 0, stream>>>(qB, kB, vB, aoH, aoL);
    mm_k<0,true,false><<<dim3(8,8,4), blk, 0, stream>>>(LWH+1572864, LWL+1572864, aoH, aoL, eB, nullptr, nullptr, 512, 512);

    statsnorm_k<<<512, blk, 0, stream>>>(eB, n2w, n2b, nBH, nBL);
    mm_k<1,false,false><<<dim3(8,32,4), blk, 0, stream>>>(LWH+2097152, LWL+2097152, nBH, nBL, nullptr, f2H, f2L, 2048, 512);
    mm_k<0,true,false><<<dim3(8,8,4), blk, 0, stream>>>(LWH+4194304, LWL+4194304, f2H, f2L, eB, nullptr, nullptr, 512, 2048);
  }

  // ---- decoder frame_block ----
  wcvt_k<2><<<dim3(1024,3), blk, 0, stream>>>(d1_pw, d2_pw, di_pw, nullptr, nullptr, nullptr, LWH, LWL);
  cvt_k<<<512, blk, 0, stream>>>(eB, ePH, ePL);
  mm_k<0,false,false><<<dim3(8,16,4), blk, 0, stream>>>(LWH, LWL, ePH, ePL, bufA, nullptr, nullptr, 1024, 512);
  dwmix_k<1><<<1024, blk, 0, stream>>>(bufA, d1_dw, nullptr, nullptr, sqH, sqL, 1024);
  mm_k<0,false,false><<<dim3(8,16,4), blk, 0, stream>>>(LWH+1048576, LWL+1048576, sqH, sqL, bufA, nullptr, nullptr, 1024, 1024);
  dwmix_k<0><<<1024, blk, 0, stream>>>(bufA, d2_dw, nullptr, Zbuf, nullptr, nullptr, 1024);
  mm_k<0,false,false><<<dim3(8,16,4), blk, 0, stream>>>(LWH+3145728, LWL+3145728, ePH, ePL, bufA, nullptr, nullptr, 1024, 512);
  out_t_k<<<dim3(8,16,2), blk, 0, stream>>>(bufA, di_dw, Zbuf, os);
}

// Round 2
// 1857.798 us; speedup vs baseline: 1.2916x; 1.0558x over previous
//
#include <hip/hip_runtime.h>
#include <math.h>

// FrameTransformer v6: counted-vmcnt pipelines (T3/T4) + plane-native attention.
// - mm_k: dbuf global_load_lds staging with s_waitcnt vmcnt(8) + raw s_barrier
//   (prefetch never drained at barriers -> stage latency hidden at 1 block/CU).
// - qkv_post emits Q/K/V as bf16 hi/lo planes (rope in fp32 first); attn_k
//   consumes planes: Q staged once (swizzled gl_lds, frags hoisted to regs),
//   K double-buffered with counted vmcnt, V reg-loaded at tile top (T14) and
//   scatter-transposed with no conversion math. 3 raw barriers per k-tile.

typedef short s16x8 __attribute__((ext_vector_type(8)));
typedef float f32x4 __attribute__((ext_vector_type(4)));
typedef unsigned short u16;
#define MFMA(a,b,c) __builtin_amdgcn_mfma_f32_16x16x32_bf16(a,b,c,0,0,0)

__device__ __forceinline__ float4 ld4(const float* p){ return *(const float4*)p; }
__device__ __forceinline__ void st4(float* p, float4 v){ *(float4*)p = v; }
__device__ __forceinline__ float4 f4fma2(float a, float4 x, float b, float4 y){
  float4 r; r.x=a*x.x+b*y.x; r.y=a*x.y+b*y.y; r.z=a*x.z+b*y.z; r.w=a*x.w+b*y.w; return r;
}
__device__ __forceinline__ float4 f4add(float4 a, float4 b){
  float4 r; r.x=a.x+b.x; r.y=a.y+b.y; r.z=a.z+b.z; r.w=a.w+b.w; return r;
}
__device__ __forceinline__ float4 f4sqrelu(float4 a){
  float4 r;
  r.x = a.x>0.f ? a.x*a.x : 0.f; r.y = a.y>0.f ? a.y*a.y : 0.f;
  r.z = a.z>0.f ? a.z*a.z : 0.f; r.w = a.w>0.f ? a.w*a.w : 0.f;
  return r;
}

// split 8 floats -> bf16 hi/lo planes (truncation; lo captures residual)
__device__ __forceinline__ void cvt8(float4 a, float4 b, s16x8* hi, s16x8* lo){
  union { s16x8 v; unsigned short u[8]; } H, L;
  float f[8] = {a.x,a.y,a.z,a.w,b.x,b.y,b.z,b.w};
  #pragma unroll
  for (int j=0;j<8;j++){
    unsigned u = __float_as_uint(f[j]);
    H.u[j] = (unsigned short)(u>>16);
    float hf = __uint_as_float(u & 0xffff0000u);
    float lf = f[j] - hf;
    L.u[j] = (unsigned short)(__float_as_uint(lf)>>16);
  }
  *hi = H.v; *lo = L.v;
}

__device__ __forceinline__ void cvt4(float4 a, ushort4* hi, ushort4* lo){
  unsigned short hh[4], ll[4];
  float f[4] = {a.x,a.y,a.z,a.w};
  #pragma unroll
  for (int j=0;j<4;j++){
    unsigned u = __float_as_uint(f[j]);
    hh[j] = (unsigned short)(u>>16);
    float hf = __uint_as_float(u & 0xffff0000u);
    ll[j] = (unsigned short)(__float_as_uint(f[j]-hf)>>16);
  }
  ushort4 H, L;
  H.x=hh[0];H.y=hh[1];H.z=hh[2];H.w=hh[3];
  L.x=ll[0];L.y=ll[1];L.z=ll[2];L.w=ll[3];
  *hi=H; *lo=L;
}

// async global->LDS, 16B per lane, wave-uniform LDS base (per-lane global src)
__device__ __forceinline__ void gl16(const void* g, void* l){
  __builtin_amdgcn_global_load_lds((const __attribute__((address_space(1))) void*)g,
                                   (__attribute__((address_space(3))) void*)l, 16, 0, 0);
}

__device__ __forceinline__ void wait_vm8(){ asm volatile("s_waitcnt vmcnt(8)" ::: "memory"); }
__device__ __forceinline__ void wait_vm4(){ asm volatile("s_waitcnt vmcnt(4)" ::: "memory"); }
__device__ __forceinline__ void wait_vm0(){ asm volatile("s_waitcnt vmcnt(0)" ::: "memory"); }
__device__ __forceinline__ void wait_lgkm0(){ asm volatile("s_waitcnt lgkmcnt(0)" ::: "memory"); }
__device__ __forceinline__ void barrier_raw(){
  __builtin_amdgcn_s_barrier();
  __builtin_amdgcn_sched_barrier(0);
}

// ---------------- rope table: cos/sin[w][j], j=0..31 ----------------
__global__ __launch_bounds__(256) void rope_tab_k(float* __restrict__ cosT, float* __restrict__ sinT){
  int idx = blockIdx.x*256 + threadIdx.x;   // 512*32
  int w = idx >> 5, j = idx & 31;
  float th = (float)w * powf(10000.f, -(float)(2*j)/64.f);
  cosT[idx] = cosf(th);
  sinT[idx] = sinf(th);
}

// ---------------- weight conversion: fp32 -> bf16 hi/lo planes ----------------
template<int VAR>
__global__ __launch_bounds__(256) void wcvt_k(
    const float* __restrict__ s0, const float* __restrict__ s1, const float* __restrict__ s2,
    const float* __restrict__ s3, const float* __restrict__ s4, const float* __restrict__ s5,
    u16* __restrict__ H, u16* __restrict__ L)
{
  const int seg = blockIdx.y;
  const float* src; int n; size_t off;
  if (VAR == 0){
    if      (seg==0){ src=s0; n= 524288; off=0; }
    else if (seg==1){ src=s1; n= 524288; off= 524288; }
    else if (seg==2){ src=s2; n= 524288; off=1048576; }
    else if (seg==3){ src=s3; n= 524288; off=1572864; }
    else if (seg==4){ src=s4; n=2097152; off=2097152; }
    else            { src=s5; n=2097152; off=4194304; }
  } else if (VAR == 1){
    if      (seg==0){ src=s0; n=1048576; off=0; }
    else if (seg==1){ src=s1; n= 524288; off=1048576; }
    else            { src=s2; n=1048576; off=1572864; }
  } else {
    if      (seg==0){ src=s0; n=1048576; off=0; }
    else if (seg==1){ src=s1; n=2097152; off=1048576; }
    else            { src=s2; n=1048576; off=3145728; }
  }
  const int idx = blockIdx.x*256 + threadIdx.x;
  if (idx*8 >= n) return;
  float4 a = ld4(src + (size_t)idx*8);
  float4 b = ld4(src + (size_t)idx*8 + 4);
  s16x8 h,l; cvt8(a,b,&h,&l);
  *(s16x8*)&H[off + (size_t)idx*8] = h;
  *(s16x8*)&L[off + (size_t)idx*8] = l;
}

// ---------------- plain fp32 -> bf16 hi/lo planes ----------------
__global__ __launch_bounds__(256) void cvt_k(const float* __restrict__ X,
                                             u16* __restrict__ H, u16* __restrict__ L){
  const int idx = blockIdx.x*256 + threadIdx.x;
  float4 a = ld4(X + (size_t)idx*8);
  float4 b = ld4(X + (size_t)idx*8 + 4);
  s16x8 h,l; cvt8(a,b,&h,&l);
  *(s16x8*)&H[(size_t)idx*8] = h;
  *(s16x8*)&L[(size_t)idx*8] = l;
}

// ---------------- fused frame-norm stats + normalize + cvt ----------------
__global__ __launch_bounds__(256) void statsnorm_k(
    const float* __restrict__ E, const float* __restrict__ G, const float* __restrict__ Bt,
    u16* __restrict__ BH, u16* __restrict__ BL)
{
  int row = (blockIdx.x<<2) + (threadIdx.x>>6);
  int lane = threadIdx.x & 63;
  int c = (row >> 9) & 1;
  const float* p = E + (size_t)row*512 + (lane<<3);
  float4 a = ld4(p), b = ld4(p+4);
  float s = a.x+a.y+a.z+a.w + b.x+b.y+b.z+b.w;
  float q = a.x*a.x+a.y*a.y+a.z*a.z+a.w*a.w + b.x*b.x+b.y*b.y+b.z*b.z+b.w*b.w;
  #pragma unroll
  for (int off=32; off; off>>=1){ s += __shfl_xor(s,off); q += __shfl_xor(q,off); }
  float mu = s*(1.f/512.f);
  float rs = rsqrtf(q*(1.f/512.f) - mu*mu + 1e-5f);
  const float* gp = G  + c*512 + (lane<<3);
  const float* bp = Bt + c*512 + (lane<<3);
  float4 g0 = ld4(gp), g1 = ld4(gp+4), b0 = ld4(bp), b1 = ld4(bp+4);
  a.x = (a.x-mu)*rs*g0.x + b0.x; a.y = (a.y-mu)*rs*g0.y + b0.y;
  a.z = (a.z-mu)*rs*g0.z + b0.z; a.w = (a.w-mu)*rs*g0.w + b0.w;
  b.x = (b.x-mu)*rs*g1.x + b1.x; b.y = (b.y-mu)*rs*g1.y + b1.y;
  b.z = (b.z-mu)*rs*g1.z + b1.z; b.w = (b.w-mu)*rs*g1.w + b1.w;
  s16x8 h,l; cvt8(a,b,&h,&l);
  size_t o = (size_t)row*512 + (lane<<3);
  *(s16x8*)&BH[o] = h; *(s16x8*)&BL[o] = l;
}

// ---------------- MFMA GEMM on bf16 hi/lo planes (counted-vmcnt pipeline) ----------------
template<int EPI, bool ACC, bool FUSE3>
__global__ __launch_bounds__(256) void mm_k(
    const u16* __restrict__ AH_, const u16* __restrict__ AL_,
    const u16* __restrict__ BH_, const u16* __restrict__ BL_,
    float* __restrict__ Y_, u16* __restrict__ YH_, u16* __restrict__ YL_,
    int M, int K)
{
  const int z = blockIdx.z;
  const int bc = FUSE3 ? (z & 3) : z;
  const int c = bc & 1;
  const size_t aoff = (size_t)c*M*K + (FUSE3 ? (size_t)(z>>2)*524288 : (size_t)0);
  const u16* AHp = AH_ + aoff;
  const u16* ALp = AL_ + aoff;
  const u16* BHp = BH_ + (size_t)bc*512*K;
  const u16* BLp = BL_ + (size_t)bc*512*K;

  const int n0 = blockIdx.x << 6, m0 = blockIdx.y << 6;
  const int t = threadIdx.x;
  const int lane = t & 63, wv = t >> 6;

  __shared__ __align__(16) unsigned char smem[65536];
  u16* sm = (u16*)smem;

  const int Rb  = wv*16 + (lane>>3);
  const int sc8 = ((lane & 7) ^ (Rb & 7)) << 3;
  const u16* gA0 = AHp + (size_t)(m0+Rb)*K + sc8;
  const u16* gA1 = ALp + (size_t)(m0+Rb)*K + sc8;
  const u16* gB0 = BHp + (size_t)(n0+Rb)*K + sc8;
  const u16* gB1 = BLp + (size_t)(n0+Rb)*K + sc8;
  const size_t r8 = (size_t)8*K;

  auto stage = [&](int half, int kt){
    u16* lb = sm + (half<<14) + (wv<<10);
    const int k64 = kt << 6;
    gl16(gA0 + k64,      lb);
    gl16(gA0 + r8 + k64, lb + 512);
    gl16(gA1 + k64,      lb + 4096);
    gl16(gA1 + r8 + k64, lb + 4608);
    gl16(gB0 + k64,      lb + 8192);
    gl16(gB0 + r8 + k64, lb + 8704);
    gl16(gB1 + k64,      lb + 12288);
    gl16(gB1 + r8 + k64, lb + 12800);
  };

  const int fr = lane & 15, fq = lane >> 4;
  const int mq = (wv >> 1) << 5, nq = (wv & 1) << 5;
  const int ra0 = (mq + fr)<<6, ra1 = (mq + 16 + fr)<<6;
  const int rb0 = (nq + fr)<<6, rb1 = (nq + 16 + fr)<<6;
  const int frx = fr & 7;

  f32x4 acc00 = {0,0,0,0}, acc01 = {0,0,0,0}, acc10 = {0,0,0,0}, acc11 = {0,0,0,0};
  const int NT = K >> 6;

  stage(0, 0);
  for (int kt = 0; kt < NT; kt++){
    const bool pf = (kt + 1 < NT);
    if (pf) stage((kt+1)&1, kt+1);
    if (pf) wait_vm8(); else wait_vm0();
    barrier_raw();
    const u16* cb = sm + ((kt&1)<<14);
    #pragma unroll
    for (int ks = 0; ks < 64; ks += 32){
      const int cs = ((((ks>>3) + fq) ^ frx) << 3);
      s16x8 aH0 = *(const s16x8*)&cb[ra0 + cs];
      s16x8 aH1 = *(const s16x8*)&cb[ra1 + cs];
      s16x8 aL0 = *(const s16x8*)&cb[4096 + ra0 + cs];
      s16x8 aL1 = *(const s16x8*)&cb[4096 + ra1 + cs];
      s16x8 bH0 = *(const s16x8*)&cb[8192 + rb0 + cs];
      s16x8 bH1 = *(const s16x8*)&cb[8192 + rb1 + cs];
      s16x8 bL0 = *(const s16x8*)&cb[12288 + rb0 + cs];
      s16x8 bL1 = *(const s16x8*)&cb[12288 + rb1 + cs];
      acc00 = MFMA(aH0,bH0,acc00); acc00 = MFMA(aH0,bL0,acc00); acc00 = MFMA(aL0,bH0,acc00);
      acc01 = MFMA(aH0,bH1,acc01); acc01 = MFMA(aH0,bL1,acc01); acc01 = MFMA(aL0,bH1,acc01);
      acc10 = MFMA(aH1,bH0,acc10); acc10 = MFMA(aH1,bL0,acc10); acc10 = MFMA(aL1,bH0,acc10);
      acc11 = MFMA(aH1,bH1,acc11); acc11 = MFMA(aH1,bL1,acc11); acc11 = MFMA(aL1,bH1,acc11);
    }
    wait_lgkm0();
    barrier_raw();
  }

  float* Yt = (float*)smem;    // [64][72]
  #pragma unroll
  for (int i=0;i<4;i++){
    Yt[(nq      + fr)*72 + mq      + fq*4 + i] = acc00[i];
    Yt[(nq + 16 + fr)*72 + mq      + fq*4 + i] = acc01[i];
    Yt[(nq      + fr)*72 + mq + 16 + fq*4 + i] = acc10[i];
    Yt[(nq + 16 + fr)*72 + mq + 16 + fq*4 + i] = acc11[i];
  }
  __syncthreads();
  const int sr = t >> 2, scB = (t & 3) << 4;
  if (EPI == 1){
    float4 r0 = f4sqrelu(*(float4*)&Yt[sr*72 + scB]);
    float4 r1 = f4sqrelu(*(float4*)&Yt[sr*72 + scB + 4]);
    float4 r2 = f4sqrelu(*(float4*)&Yt[sr*72 + scB + 8]);
    float4 r3 = f4sqrelu(*(float4*)&Yt[sr*72 + scB + 12]);
    u16* YH = YH_ + (size_t)bc*512*M;
    u16* YL = YL_ + (size_t)bc*512*M;
    size_t base = (size_t)(n0 + sr)*M + m0 + scB;
    s16x8 h,l;
    cvt8(r0,r1,&h,&l); *(s16x8*)&YH[base]   = h; *(s16x8*)&YL[base]   = l;
    cvt8(r2,r3,&h,&l); *(s16x8*)&YH[base+8] = h; *(s16x8*)&YL[base+8] = l;
  } else {
    float* Y = Y_ + (FUSE3 ? (size_t)(z>>2)*1048576 : (size_t)0) + (size_t)bc*512*M;
    #pragma unroll
    for (int i=0;i<4;i++){
      float4 r = *(float4*)&Yt[sr*72 + scB + i*4];
      float* dst = &Y[(size_t)(n0 + sr)*M + m0 + scB + i*4];
      if (ACC) r = f4add(r, ld4(dst));
      st4(dst, r);
    }
  }
}

// ---------------- channel mix (dw); MODE=1 writes sqrelu'd bf16 hi/lo planes ----------------
template<int MODE>
__global__ __launch_bounds__(256) void dwmix_k(
    const float* __restrict__ T, const float* __restrict__ dwp,
    const float* __restrict__ Z, float* __restrict__ O,
    u16* __restrict__ OH, u16* __restrict__ OL, int F)
{
  int idx = blockIdx.x*256 + threadIdx.x;
  int perb = F << 7;
  int b = idx / perb; int rem = idx - b*perb;
  size_t i0 = ((size_t)(b*2) * F)*512 + (size_t)rem*4;
  size_t i1 = i0 + (size_t)F*512;
  float4 t0 = ld4(T + i0), t1 = ld4(T + i1);
  float d00 = dwp[0], d01 = dwp[1], d10 = dwp[2], d11 = dwp[3];
  float4 o0 = f4fma2(d00, t0, d01, t1);
  float4 o1 = f4fma2(d10, t0, d11, t1);
  if (MODE == 1){
    o0 = f4sqrelu(o0); o1 = f4sqrelu(o1);
    ushort4 h,l;
    cvt4(o0,&h,&l); *(ushort4*)&OH[i0] = h; *(ushort4*)&OL[i0] = l;
    cvt4(o1,&h,&l); *(ushort4*)&OH[i1] = h; *(ushort4*)&OL[i1] = l;
  } else if (MODE == 2){
    o0 = f4add(o0, ld4(Z + i0)); o1 = f4add(o1, ld4(Z + i1));
    st4(O + i0, o0); st4(O + i1, o1);
  } else {
    st4(O + i0, o0); st4(O + i1, o1);
  }
}

// ---------------- fused qkv post: dw-mix (+rope for q,k) -> bf16 hi/lo planes ----------------
__global__ __launch_bounds__(256) void qkv_post_k(
    const float* __restrict__ QY, const float* __restrict__ qdw,
    const float* __restrict__ kdw, const float* __restrict__ vdw,
    u16* __restrict__ qHp, u16* __restrict__ qLp,
    u16* __restrict__ kHp, u16* __restrict__ kLp,
    u16* __restrict__ vHp, u16* __restrict__ vLp,
    const float* __restrict__ cosT, const float* __restrict__ sinT)
{
  int p = blockIdx.y;
  const float* T = QY + (size_t)p*1048576;
  const float* dwp = (p==0) ? qdw : ((p==1) ? kdw : vdw);
  u16* OH = (p==0) ? qHp : ((p==1) ? kHp : vHp);
  u16* OL = (p==0) ? qLp : ((p==1) ? kLp : vLp);
  int idx = blockIdx.x*256 + threadIdx.x;
  int b = idx >> 16; int rem = idx & 65535;
  int w = rem >> 7; int f = (rem & 127) << 2;
  size_t i0 = ((size_t)(b*2)*512 + w)*512 + f;
  size_t i1 = i0 + 262144;
  float4 t0 = ld4(T+i0), t1 = ld4(T+i1);
  float d00 = dwp[0], d01 = dwp[1], d10 = dwp[2], d11 = dwp[3];
  float4 o0 = f4fma2(d00, t0, d01, t1);
  float4 o1 = f4fma2(d10, t0, d11, t1);
  if (p < 2){
    int j = (f & 63) >> 1;
    float c0 = cosT[w*32 + j], c1 = cosT[w*32 + j + 1];
    float s0 = sinT[w*32 + j], s1 = sinT[w*32 + j + 1];
    float4 r0, r1;
    r0.x = o0.x*c0 - o0.y*s0;  r0.y = o0.y*c0 + o0.x*s0;
    r0.z = o0.z*c1 - o0.w*s1;  r0.w = o0.w*c1 + o0.z*s1;
    r1.x = o1.x*c0 - o1.y*s0;  r1.y = o1.y*c0 + o1.x*s0;
    r1.z = o1.z*c1 - o1.w*s1;  r1.w = o1.w*c1 + o1.z*s1;
    o0 = r0; o1 = r1;
  }
  ushort4 h,l;
  cvt4(o0,&h,&l); *(ushort4*)&OH[i0] = h; *(ushort4*)&OL[i0] = l;
  cvt4(o1,&h,&l); *(ushort4*)&OH[i1] = h; *(ushort4*)&OL[i1] = l;
}

// ---------------- transpose x -> bf16 hi/lo [bc][512 w][1024 f] ----------------
__global__ __launch_bounds__(256) void transpose_x_k(const float* __restrict__ X,
                                                     u16* __restrict__ XH, u16* __restrict__ XL){
  __shared__ float T[64][68];
  int w0 = blockIdx.x << 6, f0 = blockIdx.y << 6, bc = blockIdx.z;
  int r = threadIdx.x >> 2, c4 = (threadIdx.x & 3) << 4;
  const float* src = X + ((size_t)bc*1024 + f0 + r)*512 + w0 + c4;
  #pragma unroll
  for (int i=0;i<4;i++) st4(&T[r][c4 + i*4], ld4(src + i*4));
  __syncthreads();
  size_t base = ((size_t)bc*512 + w0 + r)*1024 + f0 + c4;
  #pragma unroll
  for (int i=0;i<2;i++){
    float4 v0, v1;
    v0.x = T[c4+i*8+0][r]; v0.y = T[c4+i*8+1][r]; v0.z = T[c4+i*8+2][r]; v0.w = T[c4+i*8+3][r];
    v1.x = T[c4+i*8+4][r]; v1.y = T[c4+i*8+5][r]; v1.z = T[c4+i*8+6][r]; v1.w = T[c4+i*8+7][r];
    s16x8 h,l; cvt8(v0,v1,&h,&l);
    *(s16x8*)&XH[base + i*8] = h;
    *(s16x8*)&XL[base + i*8] = l;
  }
}

// ---------------- final: dw-mix + add Z, transpose wf -> (b,c,1024,512) ----------------
__global__ __launch_bounds__(256) void out_t_k(const float* __restrict__ T_, const float* __restrict__ dwp,
                                               const float* __restrict__ Z, float* __restrict__ O){
  __shared__ float T0[64][68], T1[64][68];
  int w0 = blockIdx.x << 6, f0 = blockIdx.y << 6, b = blockIdx.z;
  int r = threadIdx.x >> 2, c4 = (threadIdx.x & 3) << 4;
  size_t base0 = ((size_t)(b*2)*512 + w0 + r)*1024 + f0 + c4;
  size_t base1 = base0 + 524288;
  float d00 = dwp[0], d01 = dwp[1], d10 = dwp[2], d11 = dwp[3];
  #pragma unroll
  for (int i=0;i<4;i++){
    float4 t0 = ld4(T_+base0+i*4), t1 = ld4(T_+base1+i*4);
    float4 z0 = ld4(Z+base0+i*4),  z1 = ld4(Z+base1+i*4);
    st4(&T0[r][c4+i*4], f4add(f4fma2(d00,t0,d01,t1), z0));
    st4(&T1[r][c4+i*4], f4add(f4fma2(d10,t0,d11,t1), z1));
  }
  __syncthreads();
  size_t ob0 = ((size_t)(b*2)*1024 + f0 + r)*512 + w0 + c4;
  size_t ob1 = ob0 + 524288;
  #pragma unroll
  for (int i=0;i<4;i++){
    float4 v0, v1;
    v0.x=T0[c4+i*4+0][r]; v0.y=T0[c4+i*4+1][r]; v0.z=T0[c4+i*4+2][r]; v0.w=T0[c4+i*4+3][r];
    v1.x=T1[c4+i*4+0][r]; v1.y=T1[c4+i*4+1][r]; v1.z=T1[c4+i*4+2][r]; v1.w=T1[c4+i*4+3][r];
    st4(O+ob0+i*4, v0);
    st4(O+ob1+i*4, v1);
  }
}

// ---------------- MFMA fused attention on bf16 planes ----------------
// grid (8 q-tiles, 8 heads, 4 bc); 4 waves. Q staged once (gl_lds, swizzled) and
// hoisted to regs; K dbuf via gl_lds + counted vmcnt; V reg-loaded at tile top,
// scatter-transposed (no cvt math). 3 raw barriers per k-tile.
__global__ __launch_bounds__(256) void attn_k(
    const u16* __restrict__ qHp, const u16* __restrict__ qLp,
    const u16* __restrict__ kHp, const u16* __restrict__ kLp,
    const u16* __restrict__ vHp, const u16* __restrict__ vLp,
    u16* __restrict__ aoH, u16* __restrict__ aoL)
{
  const int q0 = blockIdx.x << 6;
  const int hc = blockIdx.y << 6;
  const int bc = blockIdx.z;
  const size_t cb = (size_t)bc*262144;
  const u16* Qh = qHp + cb; const u16* Ql = qLp + cb;
  const u16* Kh = kHp + cb; const u16* Kl = kLp + cb;
  const u16* Vh = vHp + cb; const u16* Vl = vLp + cb;

  __shared__ __align__(16) u16 QHs[4096], QLs[4096];     // [64 q][64 d] swizzled
  __shared__ __align__(16) u16 KHs[8192], KLs[8192];     // 2 x [64 k'][64 d] swizzled
  __shared__ __align__(16) u16 TH[4608], TL[4608];       // V^T [64 d][72] padded
  __shared__ float St[64*68];
  __shared__ float mL[64], lL[64], aLs[64];

  const int t = threadIdx.x, lane = t & 63, wv = t >> 6;
  const int fr = lane & 15, fq = lane >> 4;
  const int mq = wv << 4;
  const int frx = fr & 7;

  // staging geometry (same swizzle family as mm_k)
  const int sR  = lane >> 3;
  const int sCh = ((lane & 7) ^ (sR & 7)) << 3;
  const int wr  = wv*16 + sR;

  // prologue: stage Q (4 gl16/wave), then K0 (4 gl16/wave)
  {
    const u16* s0 = Qh + (size_t)(q0 + wr)*512 + hc + sCh;
    u16* d0 = QHs + (wv<<10);
    gl16(s0, d0); gl16(s0 + 8*512, d0 + 512);
    const u16* s1 = Ql + (size_t)(q0 + wr)*512 + hc + sCh;
    u16* d1 = QLs + (wv<<10);
    gl16(s1, d1); gl16(s1 + 8*512, d1 + 512);
    const u16* s2 = Kh + (size_t)wr*512 + hc + sCh;
    u16* d2 = KHs + (wv<<10);
    gl16(s2, d2); gl16(s2 + 8*512, d2 + 512);
    const u16* s3 = Kl + (size_t)wr*512 + hc + sCh;
    u16* d3 = KLs + (wv<<10);
    gl16(s3, d3); gl16(s3 + 8*512, d3 + 512);
  }
  if (t < 64){ mL[t] = -1e30f; lL[t] = 0.f; }
  wait_vm4();              // Q done; K0's 4 stay in flight
  barrier_raw();

  // hoist Q fragments to registers
  s16x8 qh[2], ql[2];
  #pragma unroll
  for (int ksi = 0; ksi < 2; ksi++){
    int cs = (((ksi<<2) + fq) ^ frx) << 3;
    qh[ksi] = *(const s16x8*)&QHs[((mq+fr)<<6) + cs];
    ql[ksi] = *(const s16x8*)&QLs[((mq+fr)<<6) + cs];
  }

  f32x4 oA[4] = {{0,0,0,0},{0,0,0,0},{0,0,0,0},{0,0,0,0}};
  const float sc = 0.044194173824159216f;   // 1/sqrt(512)

  for (int kt = 0; kt < 8; kt++){
    const int k0 = kt << 6;
    // V tile loads -> regs (T14 issue-early; consumed after softmax)
    const u16* vsh = Vh + (size_t)(k0 + lane)*512 + hc + (wv<<4);
    const u16* vsl = Vl + (size_t)(k0 + lane)*512 + hc + (wv<<4);
    s16x8 vh0 = *(const s16x8*)vsh;
    s16x8 vh1 = *(const s16x8*)(vsh + 8);
    s16x8 vl0 = *(const s16x8*)vsl;
    s16x8 vl1 = *(const s16x8*)(vsl + 8);
    // K(t+1) prefetch
    if (kt < 7){
      const u16* s2 = Kh + (size_t)((kt+1)*64 + wr)*512 + hc + sCh;
      u16* d2 = KHs + (((kt+1)&1)<<12) + (wv<<10);
      gl16(s2, d2); gl16(s2 + 8*512, d2 + 512);
      const u16* s3 = Kl + (size_t)((kt+1)*64 + wr)*512 + hc + sCh;
      u16* d3 = KLs + (((kt+1)&1)<<12) + (wv<<10);
      gl16(s3, d3); gl16(s3 + 8*512, d3 + 512);
    }
    // B1: K(t) ready (keep V + K(t+1) in flight); prev PV reads retired
    wait_lgkm0();
    if (kt < 7) wait_vm8(); else wait_vm4();
    barrier_raw();
    // S = Q K^T
    {
      const int kbuf = (kt&1)<<12;
      f32x4 sA[4] = {{0,0,0,0},{0,0,0,0},{0,0,0,0},{0,0,0,0}};
      #pragma unroll
      for (int ksi = 0; ksi < 2; ksi++){
        int cs = (((ksi<<2) + fq) ^ frx) << 3;
        s16x8 aH = qh[ksi], aLo = ql[ksi];
        #pragma unroll
        for (int nt = 0; nt < 4; nt++){
          int bo = kbuf + (((nt<<4) + fr)<<6) + cs;
          s16x8 bH  = *(const s16x8*)&KHs[bo];
          s16x8 bLo = *(const s16x8*)&KLs[bo];
          sA[nt] = MFMA(aH,bH,sA[nt]);
          sA[nt] = MFMA(aLo,bH,sA[nt]);
          sA[nt] = MFMA(aH,bLo,sA[nt]);
        }
      }
      #pragma unroll
      for (int nt = 0; nt < 4; nt++)
        #pragma unroll
        for (int i = 0; i < 4; i++)
          St[(mq + fq*4 + i)*68 + (nt<<4) + fr] = sA[nt][i]*sc;
    }
    // B2: scores visible
    wait_lgkm0();
    barrier_raw();
    // online softmax
    {
      int r = t >> 2, sub = t & 3;
      float* row = &St[r*68 + (sub << 4)];
      float4 x0 = ((float4*)row)[0], x1 = ((float4*)row)[1];
      float4 x2 = ((float4*)row)[2], x3 = ((float4*)row)[3];
      float mx = fmaxf(fmaxf(fmaxf(x0.x,x0.y),fmaxf(x0.z,x0.w)),
                       fmaxf(fmaxf(x1.x,x1.y),fmaxf(x1.z,x1.w)));
      mx = fmaxf(mx, fmaxf(fmaxf(fmaxf(x2.x,x2.y),fmaxf(x2.z,x2.w)),
                           fmaxf(fmaxf(x3.x,x3.y),fmaxf(x3.z,x3.w))));
      mx = fmaxf(mx, __shfl_xor(mx, 1));
      mx = fmaxf(mx, __shfl_xor(mx, 2));
      float mo = mL[r];
      float mn = fmaxf(mo, mx);
      float al = __expf(mo - mn);
      x0.x=__expf(x0.x-mn); x0.y=__expf(x0.y-mn); x0.z=__expf(x0.z-mn); x0.w=__expf(x0.w-mn);
      x1.x=__expf(x1.x-mn); x1.y=__expf(x1.y-mn); x1.z=__expf(x1.z-mn); x1.w=__expf(x1.w-mn);
      x2.x=__expf(x2.x-mn); x2.y=__expf(x2.y-mn); x2.z=__expf(x2.z-mn); x2.w=__expf(x2.w-mn);
      x3.x=__expf(x3.x-mn); x3.y=__expf(x3.y-mn); x3.z=__expf(x3.z-mn); x3.w=__expf(x3.w-mn);
      float sm = (x0.x+x0.y+x0.z+x0.w) + (x1.x+x1.y+x1.z+x1.w)
               + (x2.x+x2.y+x2.z+x2.w) + (x3.x+x3.y+x3.z+x3.w);
      sm += __shfl_xor(sm, 1);
      sm += __shfl_xor(sm, 2);
      ((float4*)row)[0]=x0; ((float4*)row)[1]=x1; ((float4*)row)[2]=x2; ((float4*)row)[3]=x3;
      if (sub == 0){ mL[r] = mn; lL[r] = lL[r]*al + sm; aLs[r] = al; }
    }
    // V^T scatter from regs (compiler inserts the vmcnt wait for vh*/vl*)
    {
      int c16 = wv << 4;
      union { s16x8 v; u16 u[8]; } a0,a1,b0,b1;
      a0.v = vh0; a1.v = vh1; b0.v = vl0; b1.v = vl1;
      #pragma unroll
      for (int e=0;e<8;e++){
        TH[(c16+e)*72 + lane]   = a0.u[e];
        TL[(c16+e)*72 + lane]   = b0.u[e];
        TH[(c16+8+e)*72 + lane] = a1.u[e];
        TL[(c16+8+e)*72 + lane] = b1.u[e];
      }
    }
    // B3: probs + V^T + aLs ready
    wait_lgkm0();
    barrier_raw();
    // O = O*alpha + P V
    {
      float a0 = aLs[mq + fq*4 + 0], a1 = aLs[mq + fq*4 + 1];
      float a2 = aLs[mq + fq*4 + 2], a3 = aLs[mq + fq*4 + 3];
      #pragma unroll
      for (int nt = 0; nt < 4; nt++){
        oA[nt][0] *= a0; oA[nt][1] *= a1; oA[nt][2] *= a2; oA[nt][3] *= a3;
      }
      #pragma unroll
      for (int ks = 0; ks < 64; ks += 32){
        const float* pr = &St[(mq + fr)*68 + ks + fq*8];
        float4 p0 = ld4(pr), p1 = ld4(pr+4);
        s16x8 pH, pL;
        cvt8(p0, p1, &pH, &pL);
        #pragma unroll
        for (int nt = 0; nt < 4; nt++){
          int bo = ((nt<<4) + fr)*72 + ks + fq*8;
          s16x8 bH  = *(const s16x8*)&TH[bo];
          s16x8 bLo = *(const s16x8*)&TL[bo];
          oA[nt] = MFMA(pH,bH,oA[nt]);
          oA[nt] = MFMA(pL,bH,oA[nt]);
          oA[nt] = MFMA(pH,bLo,oA[nt]);
        }
      }
    }
  }
  // normalize, stage to St, coalesced plane write
  {
    float i0 = 1.f / lL[mq + fq*4 + 0], i1 = 1.f / lL[mq + fq*4 + 1];
    float i2 = 1.f / lL[mq + fq*4 + 2], i3 = 1.f / lL[mq + fq*4 + 3];
    #pragma unroll
    for (int nt = 0; nt < 4; nt++){
      St[(mq + fq*4 + 0)*68 + (nt<<4) + fr] = oA[nt][0]*i0;
      St[(mq + fq*4 + 1)*68 + (nt<<4) + fr] = oA[nt][1]*i1;
      St[(mq + fq*4 + 2)*68 + (nt<<4) + fr] = oA[nt][2]*i2;
      St[(mq + fq*4 + 3)*68 + (nt<<4) + fr] = oA[nt][3]*i3;
    }
  }
  __syncthreads();
  {
    int r = t >> 2, c16 = (t & 3) << 4;
    size_t base = cb + (size_t)(q0 + r)*512 + hc + c16;
    float4 v0 = *(float4*)&St[r*68 + c16];
    float4 v1 = *(float4*)&St[r*68 + c16 + 4];
    float4 v2 = *(float4*)&St[r*68 + c16 + 8];
    float4 v3 = *(float4*)&St[r*68 + c16 + 12];
    s16x8 h,l;
    cvt8(v0,v1,&h,&l); *(s16x8*)&aoH[base]   = h; *(s16x8*)&aoL[base]   = l;
    cvt8(v2,v3,&h,&l); *(s16x8*)&aoH[base+8] = h; *(s16x8*)&aoL[base+8] = l;
  }
}

extern "C" void kernel_launch(void* const* d_in, const int* in_sizes, int n_in,
                              void* d_out, int out_size, void* d_ws, size_t ws_size,
                              hipStream_t stream) {
  (void)in_sizes; (void)n_in; (void)out_size; (void)ws_size;
  const float* x     = (const float*)d_in[0];
  const float* e1_pw = (const float*)d_in[1];
  const float* e1_dw = (const float*)d_in[2];
  const float* e2_pw = (const float*)d_in[3];
  const float* e2_dw = (const float*)d_in[4];
  const float* ei_pw = (const float*)d_in[5];
  const float* ei_dw = (const float*)d_in[6];
  const float* n1_w  = (const float*)d_in[7];
  const float* n1_b  = (const float*)d_in[8];
  const float* q_pw  = (const float*)d_in[9];
  const float* q_dw  = (const float*)d_in[10];
  const float* k_pw  = (const float*)d_in[11];
  const float* k_dw  = (const float*)d_in[12];
  const float* v_pw  = (const float*)d_in[13];
  const float* v_dw  = (const float*)d_in[14];
  const float* o_pw  = (const float*)d_in[15];
  const float* n2_w  = (const float*)d_in[16];
  const float* n2_b  = (const float*)d_in[17];
  const float* f1_pw = (const float*)d_in[18];
  const float* f2_pw = (const float*)d_in[19];
  const float* d1_pw = (const float*)d_in[20];
  const float* d1_dw = (const float*)d_in[21];
  const float* d2_pw = (const float*)d_in[22];
  const float* d2_dw = (const float*)d_in[23];
  const float* di_pw = (const float*)d_in[24];
  const float* di_dw = (const float*)d_in[25];

  float* W    = (float*)d_ws;
  float* bufA = W;                        // 3,145,728 f
  float* eB   = W + 3145728;              // 1,048,576
  u16* qkvP = (u16*)(W + 4194304);        // 6 planes x 1,048,576 u16 (12MB)
  u16* qHp = qkvP;
  u16* qLp = qHp + 1048576;
  u16* kHp = qLp + 1048576;
  u16* kLp = kHp + 1048576;
  u16* vHp = kLp + 1048576;
  u16* vLp = vHp + 1048576;
  float* Zbuf = W + 7340032;              // 2,097,152
  float* cosT = W + 9437184;              // 16,384
  float* sinT = W + 9453568;              // 16,384
  u16* P   = (u16*)(W + 9469952);         // bf16 plane pool
  u16* xTH = P;                           // 2,097,152
  u16* xTL = xTH + 2097152;
  u16* nBH = xTL + 2097152;               // 1,048,576
  u16* nBL = nBH + 1048576;
  u16* aoH = nBL + 1048576;               // 1,048,576
  u16* aoL = aoH + 1048576;
  u16* f2H = aoL + 1048576;               // 4,194,304
  u16* f2L = f2H + 4194304;
  u16* sqH = f2L + 4194304;               // 2,097,152
  u16* sqL = sqH + 2097152;
  u16* ePH = sqL + 2097152;               // 1,048,576
  u16* ePL = ePH + 1048576;
  u16* LWH = ePL + 1048576;               // 6,291,456 (per-layer weight planes)
  u16* LWL = LWH + 6291456;
  float* os = (float*)d_out;

  const dim3 blk(256);

  rope_tab_k<<<64, blk, 0, stream>>>(cosT, sinT);
  transpose_x_k<<<dim3(8,16,4), blk, 0, stream>>>(x, xTH, xTL);

  // ---- encoder frame_block ----
  wcvt_k<1><<<dim3(512,3), blk, 0, stream>>>(e1_pw, e2_pw, ei_pw, nullptr, nullptr, nullptr, LWH, LWL);
  mm_k<0,false,false><<<dim3(8,8,4), blk, 0, stream>>>(LWH, LWL, xTH, xTL, bufA, nullptr, nullptr, 512, 1024);
  dwmix_k<1><<<512, blk, 0, stream>>>(bufA, e1_dw, nullptr, nullptr, sqH, sqL, 512);
  mm_k<0,false,false><<<dim3(8,8,4), blk, 0, stream>>>(LWH+1048576, LWL+1048576, sqH, sqL, bufA, nullptr, nullptr, 512, 512);
  dwmix_k<0><<<512, blk, 0, stream>>>(bufA, e2_dw, nullptr, Zbuf, nullptr, nullptr, 512);
  mm_k<0,false,false><<<dim3(8,8,4), blk, 0, stream>>>(LWH+1572864, LWL+1572864, xTH, xTL, bufA, nullptr, nullptr, 512, 1024);
  dwmix_k<2><<<512, blk, 0, stream>>>(bufA, ei_dw, Zbuf, eB, nullptr, nullptr, 512);

  // ---- 12 layers ----
  for (int i = 0; i < 12; i++){
    const float* n1w = n1_w + i*1024; const float* n1b = n1_b + i*1024;
    const float* n2w = n2_w + i*1024; const float* n2b = n2_b + i*1024;
    size_t qo = (size_t)i*524288, fo = (size_t)i*2097152;

    wcvt_k<0><<<dim3(1024,6), blk, 0, stream>>>(q_pw+qo, k_pw+qo, v_pw+qo, o_pw+qo, f1_pw+fo, f2_pw+fo, LWH, LWL);
    statsnorm_k<<<512, blk, 0, stream>>>(eB, n1w, n1b, nBH, nBL);
    mm_k<0,false,true><<<dim3(8,8,12), blk, 0, stream>>>(LWH, LWL, nBH, nBL, bufA, nullptr, nullptr, 512, 512);
    qkv_post_k<<<dim3(512,3), blk, 0, stream>>>(bufA, q_dw+i*4, k_dw+i*4, v_dw+i*4,
                                                qHp, qLp, kHp, kLp, vHp, vLp, cosT, sinT);
    attn_k<<<dim3(8,8,4), blk, 0, stream>>>(qHp, qLp, kHp, kLp, vHp, vLp, aoH, aoL);
    mm_k<0,true,false><<<dim3(8,8,4), blk, 0, stream>>>(LWH+1572864, LWL+1572864, aoH, aoL, eB, nullptr, nullptr, 512, 512);

    statsnorm_k<<<512, blk, 0, stream>>>(eB, n2w, n2b, nBH, nBL);
    mm_k<1,false,false><<<dim3(8,32,4), blk, 0, stream>>>(LWH+2097152, LWL+2097152, nBH, nBL, nullptr, f2H, f2L, 2048, 512);
    mm_k<0,true,false><<<dim3(8,8,4), blk, 0, stream>>>(LWH+4194304, LWL+4194304, f2H, f2L, eB, nullptr, nullptr, 512, 2048);
  }

  // ---- decoder frame_block ----
  wcvt_k<2><<<dim3(1024,3), blk, 0, stream>>>(d1_pw, d2_pw, di_pw, nullptr, nullptr, nullptr, LWH, LWL);
  cvt_k<<<512, blk, 0, stream>>>(eB, ePH, ePL);
  mm_k<0,false,false><<<dim3(8,16,4), blk, 0, stream>>>(LWH, LWL, ePH, ePL, bufA, nullptr, nullptr, 1024, 512);
  dwmix_k<1><<<1024, blk, 0, stream>>>(bufA, d1_dw, nullptr, nullptr, sqH, sqL, 1024);
  mm_k<0,false,false><<<dim3(8,16,4), blk, 0, stream>>>(LWH+1048576, LWL+1048576, sqH, sqL, bufA, nullptr, nullptr, 1024, 1024);
  dwmix_k<0><<<1024, blk, 0, stream>>>(bufA, d2_dw, nullptr, Zbuf, nullptr, nullptr, 1024);
  mm_k<0,false,false><<<dim3(8,16,4), blk, 0, stream>>>(LWH+3145728, LWL+3145728, ePH, ePL, bufA, nullptr, nullptr, 1024, 512);
  out_t_k<<<dim3(8,16,2), blk, 0, stream>>>(bufA, di_dw, Zbuf, os);
}